// Round 3
// baseline (459.995 us; speedup 1.0000x reference)
//
#include <hip/hip_runtime.h>

// ---------------- constants ----------------
#define BB   16
#define TT   512
#define CC   1024
#define DD   4096
#define NN   (BB*TT)        // 8192
#define NWIN 127
#define KTOP 128

typedef __attribute__((ext_vector_type(8))) unsigned short ushort8;
typedef _Float16 half8 __attribute__((ext_vector_type(8)));
typedef __attribute__((ext_vector_type(4))) float f32x4;

// ---------------- helpers ----------------
__device__ __forceinline__ unsigned short f2h(float f) {
    union { _Float16 h; unsigned short u; } c;
    c.h = (_Float16)f;   // RNE
    return c.u;
}
__device__ __forceinline__ float h2f(unsigned short u) {
    union { unsigned short u; _Float16 h; } c;
    c.u = u;
    return (float)c.h;
}
__device__ __forceinline__ unsigned tokey(float f) {
    unsigned u = __float_as_uint(f);
    return (u & 0x80000000u) ? ~u : (u | 0x80000000u);
}
__device__ __forceinline__ void async_lds16(const void* g, void* l) {
    __builtin_amdgcn_global_load_lds((const __attribute__((address_space(1))) void*)g,
                                     (__attribute__((address_space(3))) void*)l, 16, 0, 0);
}

// 8-phase fencing: reads/stages issue first, MFMA cluster after, ONE barrier/phase.
// Compiler inserts precise counted lgkmcnt for the cross-phase read->MFMA deps.
#define PH_MID()  do { __builtin_amdgcn_sched_barrier(0); __builtin_amdgcn_s_setprio(1); } while (0)
#define PH_TAIL() do { __builtin_amdgcn_s_setprio(0); __builtin_amdgcn_sched_barrier(0); \
                       __builtin_amdgcn_s_barrier(); __builtin_amdgcn_sched_barrier(0); } while (0)
#define PH_TAIL_G() do { __builtin_amdgcn_s_setprio(0); __builtin_amdgcn_sched_barrier(0); \
                         asm volatile("s_waitcnt vmcnt(4)" ::: "memory"); \
                         __builtin_amdgcn_s_barrier(); __builtin_amdgcn_sched_barrier(0); } while (0)

// wave-level scans (64 lanes)
__device__ __forceinline__ unsigned wave_prefix_incl(unsigned v) {
    int lane = threadIdx.x & 63;
#pragma unroll
    for (int off = 1; off < 64; off <<= 1) {
        unsigned n = __shfl_up(v, off, 64);
        if (lane >= off) v += n;
    }
    return v;
}
__device__ __forceinline__ unsigned wave_suffix_incl(unsigned v) {
    int lane = threadIdx.x & 63;
#pragma unroll
    for (int off = 1; off < 64; off <<= 1) {
        unsigned n = __shfl_down(v, off, 64);
        if (lane + off < 64) v += n;
    }
    return v;
}

// ---------------- top-128 radix select (dense, used by winsum) ----------------
__device__ __forceinline__ unsigned select_top128(const unsigned* keys,
                                                  unsigned* hist, unsigned* shx) {
    const int tid = threadIdx.x, wid = tid >> 6, lane = tid & 63;
    const unsigned ZKEY = 0x80000000u;
    unsigned cpos = 0, cz = 0;
#pragma unroll
    for (int i = 0; i < 16; ++i) {
        cpos += (keys[i] > ZKEY);
        cz   += (keys[i] == ZKEY);
    }
    unsigned ppos = wave_prefix_incl(cpos);
    unsigned pz   = wave_prefix_incl(cz);
    if (lane == 63) { shx[wid] = ppos; shx[4 + wid] = pz; }
    __syncthreads();
    unsigned nz = shx[0] + shx[1] + shx[2] + shx[3];
    unsigned selbits = 0u;
    if (nz <= KTOP) {
        unsigned need = KTOP - nz;
        unsigned zr = pz - cz;
        if (wid > 0) zr += shx[4];
        if (wid > 1) zr += shx[5];
        if (wid > 2) zr += shx[6];
#pragma unroll
        for (int i = 0; i < 16; ++i) {
            bool sel = (keys[i] > ZKEY) || (keys[i] == ZKEY && zr < need);
            if (keys[i] == ZKEY) ++zr;
            selbits |= (sel ? 1u : 0u) << i;
        }
        return selbits;
    }
    unsigned k2[16];
#pragma unroll
    for (int i = 0; i < 16; ++i) k2[i] = (keys[i] > ZKEY) ? keys[i] : 0u;
    unsigned prefix = 0u, pmask = 0u, Kr = KTOP;
    for (int shift = 24; shift >= 0; shift -= 8) {
        hist[tid] = 0u; hist[256 + tid] = 0u; hist[512 + tid] = 0u; hist[768 + tid] = 0u;
        __syncthreads();
        unsigned* h = hist + (wid << 8);
#pragma unroll
        for (int i = 0; i < 16; ++i)
            if (k2[i] && (k2[i] & pmask) == prefix) atomicAdd(&h[(k2[i] >> shift) & 255u], 1u);
        __syncthreads();
        unsigned v = hist[tid] + hist[256 + tid] + hist[512 + tid] + hist[768 + tid];
        unsigned s = wave_suffix_incl(v);
        if (lane == 0) shx[wid] = s;
        __syncthreads();
        unsigned stot = s;
        if (wid == 0) stot += shx[1] + shx[2] + shx[3];
        else if (wid == 1) stot += shx[2] + shx[3];
        else if (wid == 2) stot += shx[3];
        unsigned above = stot - v;
        if (stot >= Kr && above < Kr) { shx[8] = (unsigned)tid; shx[9] = Kr - above; }
        __syncthreads();
        prefix |= shx[8] << shift;
        pmask |= 0xFFu << shift;
        Kr = shx[9];
    }
    unsigned T = prefix, need = Kr;
    unsigned ce = 0;
#pragma unroll
    for (int i = 0; i < 16; ++i) ce += (k2[i] == T);
    unsigned pe = wave_prefix_incl(ce);
    __syncthreads();
    if (lane == 63) shx[4 + wid] = pe;
    __syncthreads();
    unsigned er = pe - ce;
    if (wid > 0) er += shx[4];
    if (wid > 1) er += shx[5];
    if (wid > 2) er += shx[6];
#pragma unroll
    for (int i = 0; i < 16; ++i) {
        bool sel = (k2[i] > T) || (k2[i] == T && er < need);
        if (k2[i] == T) ++er;
        selbits |= (sel ? 1u : 0u) << i;
    }
    return selbits;
}

// ---------------- merged converts + pooled/sae zeroing ----------------
__global__ __launch_bounds__(256) void k_convert_all(const float* __restrict__ x,
                                                     const float* __restrict__ Wenc,
                                                     const float* __restrict__ Wdec,
                                                     const float* __restrict__ bdec,
                                                     unsigned short* __restrict__ xh,
                                                     unsigned short* __restrict__ wh,
                                                     unsigned short* __restrict__ wdh,
                                                     float* __restrict__ pooled_zero) {
    const int bid = blockIdx.x;
    if (bid < 8192) {
        size_t i = (size_t)bid * 256 + threadIdx.x;       // x: 2M float4s
        float4 v = ((const float4*)x)[i];
        size_t c = (i * 4) & (CC - 1);
        v.x -= bdec[c]; v.y -= bdec[c + 1]; v.z -= bdec[c + 2]; v.w -= bdec[c + 3];
        uint2 o;
        o.x = (unsigned)f2h(v.x) | ((unsigned)f2h(v.y) << 16);
        o.y = (unsigned)f2h(v.z) | ((unsigned)f2h(v.w) << 16);
        ((uint2*)xh)[i] = o;
    } else if (bid < 12288) {
        size_t i = (size_t)(bid - 8192) * 256 + threadIdx.x;  // Wenc: 1M float4s
        float4 v = ((const float4*)Wenc)[i];
        uint2 o;
        o.x = (unsigned)f2h(v.x) | ((unsigned)f2h(v.y) << 16);
        o.y = (unsigned)f2h(v.z) | ((unsigned)f2h(v.w) << 16);
        ((uint2*)wh)[i] = o;
    } else if (bid < 16384) {
        size_t i = (size_t)(bid - 12288) * 256 + threadIdx.x; // Wdec: 1M float4s -> fp16
        float4 v = ((const float4*)Wdec)[i];
        uint2 o;
        o.x = (unsigned)f2h(v.x) | ((unsigned)f2h(v.y) << 16);
        o.y = (unsigned)f2h(v.z) | ((unsigned)f2h(v.w) << 16);
        ((uint2*)wdh)[i] = o;
    } else {
        const int n4 = (BB * DD + 64) / 4;
        for (int i = threadIdx.x; i < n4; i += 256)
            ((float4*)pooled_zero)[i] = make_float4(0.f, 0.f, 0.f, 0.f);
    }
}

// =====================================================================
// GEMM1: 256x256 tile, BK=64, 8 waves, 8-phase schedule with one-phase-
// ahead ds_read pre-fetch (reads for phase p+1 overlap MFMA of phase p).
// Gates: vmcnt(4) at ph3/ph7. One s_barrier per phase.
// LDS: [buf][region A0,A1,B0,B1][128*64] fp16 = 128 KiB.
// =====================================================================
__global__ __launch_bounds__(512, 1) void k_gemm_enc_256(const unsigned short* __restrict__ Ah,
                                                         const unsigned short* __restrict__ Bh,
                                                         const float* __restrict__ bias,
                                                         unsigned short* __restrict__ Cout,
                                                         float* __restrict__ gsum) {
    __shared__ __align__(16) unsigned short lds[2][4][128 * 64];
    const int tid = threadIdx.x, w = tid >> 6, lane = tid & 63;
    const int bm = blockIdx.y * 256, bn = blockIdx.x * 256;
    const int wr = w >> 2, wc = w & 3;
    const int rA = lane & 15, q = lane >> 4;
    const int sc0 = (q ^ (rA & 7)) << 3, sc1 = ((4 + q) ^ (rA & 7)) << 3;
    const int s_rt = w * 16 + (lane >> 3);
    const int s_ct = ((lane & 7) ^ (lane >> 3)) * 8;
    const unsigned short* Abase = Ah + ((size_t)(bm + s_rt)) * 1024 + s_ct;
    const unsigned short* Bbase = Bh + ((size_t)(bn + s_rt)) * 1024 + s_ct;

    auto STAGE = [&](const unsigned short* gb, int rowoff, int kt, unsigned short* reg) {
        const unsigned short* g = gb + (size_t)rowoff * 1024 + (kt << 6);
        async_lds16(g, reg + w * 1024);
        async_lds16(g + 8 * 1024, reg + w * 1024 + 512);
    };

    half8 a0[4][2], a1[4][2], b0[2][2], b1[2][2];
    f32x4 acc[8][4] = {};

    auto RDA = [&](half8 (&dst)[4][2], const unsigned short* reg) {
#pragma unroll
        for (int mf = 0; mf < 4; ++mf) {
            const unsigned short* p = reg + (wr * 64 + mf * 16 + rA) * 64;
            dst[mf][0] = *(const half8*)(p + sc0);
            dst[mf][1] = *(const half8*)(p + sc1);
        }
    };
    auto RDB = [&](half8 (&dst)[2][2], const unsigned short* reg) {
#pragma unroll
        for (int nf = 0; nf < 2; ++nf) {
            const unsigned short* p = reg + (wc * 32 + nf * 16 + rA) * 64;
            dst[nf][0] = *(const half8*)(p + sc0);
            dst[nf][1] = *(const half8*)(p + sc1);
        }
    };
    auto MF = [&](half8 (&aa)[4][2], half8 (&bb)[2][2], int mb, int nb) {
#pragma unroll
        for (int kk = 0; kk < 2; ++kk)
#pragma unroll
            for (int mf = 0; mf < 4; ++mf)
#pragma unroll
                for (int nf = 0; nf < 2; ++nf)
                    acc[mb + mf][nb + nf] = __builtin_amdgcn_mfma_f32_16x16x32_f16(
                        aa[mf][kk], bb[nf][kk], acc[mb + mf][nb + nf], 0, 0, 0);
    };

    // prologue: tile0 (A0,B0,A1,B1) -> buf0; tile1 (A0,B0,A1) -> buf1
    STAGE(Abase,   0, 0, lds[0][0]);
    STAGE(Bbase,   0, 0, lds[0][2]);
    STAGE(Abase, 128, 0, lds[0][1]);
    STAGE(Bbase, 128, 0, lds[0][3]);
    STAGE(Abase,   0, 1, lds[1][0]);
    STAGE(Bbase,   0, 1, lds[1][2]);
    STAGE(Abase, 128, 1, lds[1][1]);
    asm volatile("s_waitcnt vmcnt(6)" ::: "memory");   // drain tile0 fully
    __builtin_amdgcn_s_barrier();
    __builtin_amdgcn_sched_barrier(0);
    RDA(a0, lds[0][0]);          // pre-read for ph1
    RDB(b0, lds[0][2]);

    for (int i = 0; i < 8; ++i) {          // 2 K-tiles per iter, 16 K-tiles total
        const int ko  = (2 * i + 1) & 15;
        const int ke  = (2 * i + 2) & 15;
        const int ko2 = (2 * i + 3) & 15;
        // ph1: MF A0e x B0e ; pre-read B1e ; stage B1o
        RDB(b1, lds[0][3]);
        STAGE(Bbase, 128, ko, lds[1][3]);
        PH_MID(); MF(a0, b0, 0, 0); PH_TAIL();
        // ph2: MF A0e x B1e ; pre-read A1e ; stage A0e'
        RDA(a1, lds[0][1]);
        STAGE(Abase, 0, ke, lds[0][0]);
        PH_MID(); MF(a0, b1, 0, 2); PH_TAIL();
        // ph3: MF A1e x B0e ; stage B0e' ; GATE (drains tile-o regions)
        STAGE(Bbase, 0, ke, lds[0][2]);
        PH_MID(); MF(a1, b0, 4, 0); PH_TAIL_G();
        // ph4: MF A1e x B1e ; pre-read A0o,B0o ; stage A1e'
        RDA(a0, lds[1][0]);
        RDB(b0, lds[1][2]);
        STAGE(Abase, 128, ke, lds[0][1]);
        PH_MID(); MF(a1, b1, 4, 2); PH_TAIL();
        // ph5: MF A0o x B0o ; pre-read B1o ; stage B1e'
        RDB(b1, lds[1][3]);
        STAGE(Bbase, 128, ke, lds[0][3]);
        PH_MID(); MF(a0, b0, 0, 0); PH_TAIL();
        // ph6: MF A0o x B1o ; pre-read A1o ; stage A0o'
        RDA(a1, lds[1][1]);
        STAGE(Abase, 0, ko2, lds[1][0]);
        PH_MID(); MF(a0, b1, 0, 2); PH_TAIL();
        // ph7: MF A1o x B0o ; stage B0o' ; GATE (drains tile-e' regions)
        STAGE(Bbase, 0, ko2, lds[1][2]);
        PH_MID(); MF(a1, b0, 4, 0); PH_TAIL_G();
        // ph8: MF A1o x B1o ; pre-read A0e',B0e' ; stage A1o'
        RDA(a0, lds[0][0]);
        RDB(b0, lds[0][2]);
        STAGE(Abase, 128, ko2, lds[1][1]);
        PH_MID(); MF(a1, b1, 4, 2); PH_TAIL();
    }

    // ---------------- epilogue: bias+relu -> fp16 Cout, fused gsum ----------------
    asm volatile("s_waitcnt vmcnt(0)" ::: "memory");
    __syncthreads();
    float* cbuf = (float*)&lds[0][0][0];   // [128][256] fp32, bank-XOR-swizzled
    const int cl = rA, qr = q * 4;
    float bv[4];
#pragma unroll
    for (int nf = 0; nf < 4; ++nf)
        bv[nf] = bias[bn + ((nf < 2) ? wc * 32 + nf * 16 : 128 + wc * 32 + (nf - 2) * 16) + cl];
    const int rg = tid >> 4, seg = tid & 15;
#pragma unroll
    for (int p = 0; p < 2; ++p) {
        if (p) __syncthreads();
#pragma unroll
        for (int mf = 0; mf < 4; ++mf) {
            int lrow0 = wr * 64 + mf * 16 + qr;
#pragma unroll
            for (int nf = 0; nf < 4; ++nf) {
                int col = ((nf < 2) ? wc * 32 + nf * 16 : 128 + wc * 32 + (nf - 2) * 16) + cl;
#pragma unroll
                for (int r = 0; r < 4; ++r) {
                    int lrow = lrow0 + r;
                    float v = acc[p * 4 + mf][nf][r] + bv[nf];
                    v = v > 0.f ? v : 0.f;
                    cbuf[lrow * 256 + (col ^ (((lrow >> 2) & 7) << 2))] = v;
                }
            }
        }
        __syncthreads();
        f32x4 gs0 = {}, gs1 = {}, gs2 = {}, gs3 = {};
#pragma unroll
        for (int i2 = 0; i2 < 4; ++i2) {
            const int lrow = rg * 4 + i2;
            const f32x4* crow = (const f32x4*)cbuf + lrow * 64;
            f32x4 v0 = crow[(seg * 4 + 0) ^ (rg & 7)];
            f32x4 v1 = crow[(seg * 4 + 1) ^ (rg & 7)];
            f32x4 v2 = crow[(seg * 4 + 2) ^ (rg & 7)];
            f32x4 v3 = crow[(seg * 4 + 3) ^ (rg & 7)];
            uint4 o0, o1;
            o0.x = (unsigned)f2h(v0[0]) | ((unsigned)f2h(v0[1]) << 16);
            o0.y = (unsigned)f2h(v0[2]) | ((unsigned)f2h(v0[3]) << 16);
            o0.z = (unsigned)f2h(v1[0]) | ((unsigned)f2h(v1[1]) << 16);
            o0.w = (unsigned)f2h(v1[2]) | ((unsigned)f2h(v1[3]) << 16);
            o1.x = (unsigned)f2h(v2[0]) | ((unsigned)f2h(v2[1]) << 16);
            o1.y = (unsigned)f2h(v2[2]) | ((unsigned)f2h(v2[3]) << 16);
            o1.z = (unsigned)f2h(v3[0]) | ((unsigned)f2h(v3[1]) << 16);
            o1.w = (unsigned)f2h(v3[2]) | ((unsigned)f2h(v3[3]) << 16);
            size_t gr = (size_t)(bm + p * 128 + lrow) * 4096 + bn + seg * 16;
            *(uint4*)&Cout[gr] = o0;
            *(uint4*)&Cout[gr + 8] = o1;
            gs0 += v0; gs1 += v1; gs2 += v2; gs3 += v3;
        }
        if (gsum) {
            size_t gr = ((size_t)(bm >> 2) + p * 32 + rg) * 4096 + bn + seg * 16;
            *(f32x4*)&gsum[gr + 0]  = gs0;
            *(f32x4*)&gsum[gr + 4]  = gs1;
            *(f32x4*)&gsum[gr + 8]  = gs2;
            *(f32x4*)&gsum[gr + 12] = gs3;
        }
    }
}

// =====================================================================
// GEMM2: 256x128 tile, BK=64, 8 waves (4Mx2N), 8-phase + pre-read.
// Gates vmcnt(4) at ph3/ph7. recon + fused sae loss. LDS 96 KiB.
// =====================================================================
__global__ __launch_bounds__(512, 1) void k_gemm_recon_256(const unsigned short* __restrict__ Ap,
                                                           const unsigned short* __restrict__ Bp,
                                                           const float* __restrict__ bdec,
                                                           const float* __restrict__ X,
                                                           float* __restrict__ sae) {
    __shared__ __align__(16) unsigned short lds[2][3][128 * 64];
    __shared__ float red[512];
    const int tid = threadIdx.x, w = tid >> 6, lane = tid & 63;
    const int bm = blockIdx.y * 256, bn = blockIdx.x * 128;
    const int wr = w >> 1, wc = w & 1;
    const int rA = lane & 15, q = lane >> 4;
    const int sc0 = (q ^ (rA & 7)) << 3, sc1 = ((4 + q) ^ (rA & 7)) << 3;
    const int s_rt = w * 16 + (lane >> 3);
    const int s_ct = ((lane & 7) ^ (lane >> 3)) * 8;
    const unsigned short* Abase = Ap + ((size_t)(bm + s_rt)) * 4096 + s_ct;
    const unsigned short* Bbase = Bp + ((size_t)(bn + s_rt)) * 4096 + s_ct;

    auto STAGE = [&](const unsigned short* gb, int rowoff, int kt, unsigned short* reg) {
        const unsigned short* g = gb + (size_t)rowoff * 4096 + (kt << 6);
        async_lds16(g, reg + w * 1024);
        async_lds16(g + 8 * 4096, reg + w * 1024 + 512);
    };

    half8 a0[2][2], a1[2][2], b0[2][2], b1[2][2];
    f32x4 acc[4][4] = {};

    auto RDA = [&](half8 (&dst)[2][2], const unsigned short* reg) {
#pragma unroll
        for (int mf = 0; mf < 2; ++mf) {
            const unsigned short* p = reg + (wr * 32 + mf * 16 + rA) * 64;
            dst[mf][0] = *(const half8*)(p + sc0);
            dst[mf][1] = *(const half8*)(p + sc1);
        }
    };
    auto RDB = [&](half8 (&dst)[2][2], const unsigned short* reg, int rofs) {
#pragma unroll
        for (int nf = 0; nf < 2; ++nf) {
            const unsigned short* p = reg + (rofs + wc * 32 + nf * 16 + rA) * 64;
            dst[nf][0] = *(const half8*)(p + sc0);
            dst[nf][1] = *(const half8*)(p + sc1);
        }
    };
    auto MF = [&](half8 (&aa)[2][2], half8 (&bb)[2][2], int mb, int nb) {
#pragma unroll
        for (int kk = 0; kk < 2; ++kk)
#pragma unroll
            for (int mf = 0; mf < 2; ++mf)
#pragma unroll
                for (int nf = 0; nf < 2; ++nf)
                    acc[mb + mf][nb + nf] = __builtin_amdgcn_mfma_f32_16x16x32_f16(
                        aa[mf][kk], bb[nf][kk], acc[mb + mf][nb + nf], 0, 0, 0);
    };

    // prologue: tile0 (A0,B,A1) -> buf0; tile1 (A0,B) -> buf1
    STAGE(Abase,   0, 0, lds[0][0]);
    STAGE(Bbase,   0, 0, lds[0][2]);
    STAGE(Abase, 128, 0, lds[0][1]);
    STAGE(Abase,   0, 1, lds[1][0]);
    STAGE(Bbase,   0, 1, lds[1][2]);
    asm volatile("s_waitcnt vmcnt(4)" ::: "memory");   // drain tile0 fully
    __builtin_amdgcn_s_barrier();
    __builtin_amdgcn_sched_barrier(0);
    RDA(a0, lds[0][0]);
    RDB(b0, lds[0][2], 0);

    for (int i = 0; i < 32; ++i) {         // 2 K-tiles per iter, 64 K-tiles total
        const int ko  = (2 * i + 1) & 63;
        const int ke  = (2 * i + 2) & 63;
        const int ko2 = (2 * i + 3) & 63;
        // ph1: MF A0e x Blo-e ; pre-read Bhi-e ; stage A1o
        RDB(b1, lds[0][2], 64);
        STAGE(Abase, 128, ko, lds[1][1]);
        PH_MID(); MF(a0, b0, 0, 0); PH_TAIL();
        // ph2: MF A0e x Bhi-e ; pre-read A1e ; stage A0e'
        RDA(a1, lds[0][1]);
        STAGE(Abase, 0, ke, lds[0][0]);
        PH_MID(); MF(a0, b1, 0, 2); PH_TAIL();
        // ph3: MF A1e x Blo-e ; stage Be' ; GATE
        STAGE(Bbase, 0, ke, lds[0][2]);
        PH_MID(); MF(a1, b0, 2, 0); PH_TAIL_G();
        // ph4: MF A1e x Bhi-e ; pre-read A0o,Blo-o
        RDA(a0, lds[1][0]);
        RDB(b0, lds[1][2], 0);
        PH_MID(); MF(a1, b1, 2, 2); PH_TAIL();
        // ph5: MF A0o x Blo-o ; pre-read Bhi-o ; stage A1e'
        RDB(b1, lds[1][2], 64);
        STAGE(Abase, 128, ke, lds[0][1]);
        PH_MID(); MF(a0, b0, 0, 0); PH_TAIL();
        // ph6: MF A0o x Bhi-o ; pre-read A1o ; stage A0o'
        RDA(a1, lds[1][1]);
        STAGE(Abase, 0, ko2, lds[1][0]);
        PH_MID(); MF(a0, b1, 0, 2); PH_TAIL();
        // ph7: MF A1o x Blo-o ; stage Bo' ; GATE
        STAGE(Bbase, 0, ko2, lds[1][2]);
        PH_MID(); MF(a1, b0, 2, 0); PH_TAIL_G();
        // ph8: MF A1o x Bhi-o ; pre-read A0e',Blo-e'
        RDA(a0, lds[0][0]);
        RDB(b0, lds[0][2], 0);
        PH_MID(); MF(a1, b1, 2, 2); PH_TAIL();
    }

    // ---------------- epilogue: fused sae ----------------
    asm volatile("s_waitcnt vmcnt(0)" ::: "memory");
    const int cl = rA, qr = q * 4;
    float lsum = 0.f;
#pragma unroll
    for (int mf = 0; mf < 4; ++mf) {
        int row0 = bm + ((mf < 2) ? wr * 32 + mf * 16 : 128 + wr * 32 + (mf - 2) * 16) + qr;
#pragma unroll
        for (int nf = 0; nf < 4; ++nf) {
            int col = bn + ((nf < 2) ? wc * 32 + nf * 16 : 64 + wc * 32 + (nf - 2) * 16) + cl;
            float bvv = bdec[col];
#pragma unroll
            for (int r = 0; r < 4; ++r) {
                float v = acc[mf][nf][r] + bvv - X[(size_t)(row0 + r) * 1024 + col];
                lsum += v * v;
            }
        }
    }
    red[tid] = lsum;
    __syncthreads();
    for (int s = 256; s > 0; s >>= 1) { if (tid < s) red[tid] += red[tid + s]; __syncthreads(); }
    if (tid == 0) atomicAdd(sae, red[0]);
}

// ---------------- window top-128 from fused group sums ----------------
__global__ __launch_bounds__(256) void k_winsum_g(const float* __restrict__ gsum,
                                                  unsigned* __restrict__ wmask) {
    __shared__ unsigned hist[1024];
    __shared__ unsigned shx[16];
    __shared__ unsigned short halves[256];
    const int tid = threadIdx.x, w = blockIdx.x, b = blockIdx.y;
    const float* g0 = gsum + ((size_t)(b * 128 + w)) * DD + tid * 16;
    const float* g1 = g0 + DD;
    unsigned keys[16];
#pragma unroll
    for (int q = 0; q < 4; ++q) {
        float4 u = *(const float4*)(g0 + q * 4);
        float4 v = *(const float4*)(g1 + q * 4);
        keys[q * 4 + 0] = tokey(u.x + v.x);
        keys[q * 4 + 1] = tokey(u.y + v.y);
        keys[q * 4 + 2] = tokey(u.z + v.z);
        keys[q * 4 + 3] = tokey(u.w + v.w);
    }
    unsigned selbits = select_top128(keys, hist, shx);
    halves[tid] = (unsigned short)selbits;
    __syncthreads();
    if (tid < 128)
        wmask[(size_t)(b * NWIN + w) * 128 + tid] =
            (unsigned)halves[2 * tid] | ((unsigned)halves[2 * tid + 1] << 16);
}

// fallback: window sums read from fp16 post directly (if ws too small for gsum)
__global__ __launch_bounds__(256) void k_winsum_p(const unsigned short* __restrict__ post,
                                                  unsigned* __restrict__ wmask) {
    __shared__ unsigned hist[1024];
    __shared__ unsigned shx[16];
    __shared__ unsigned short halves[256];
    const int tid = threadIdx.x, w = blockIdx.x, b = blockIdx.y;
    const unsigned short* base = post + (size_t)(b * TT + w * 4) * DD + tid * 16;
    float s[16] = {};
#pragma unroll
    for (int j = 0; j < 8; ++j) {
        const unsigned short* rp = base + (size_t)j * DD;
        ushort8 u0 = *(const ushort8*)rp;
        ushort8 u1 = *(const ushort8*)(rp + 8);
#pragma unroll
        for (int i = 0; i < 8; ++i) { s[i] += h2f(u0[i]); s[8 + i] += h2f(u1[i]); }
    }
    unsigned keys[16];
#pragma unroll
    for (int i = 0; i < 16; ++i) keys[i] = tokey(s[i]);
    unsigned selbits = select_top128(keys, hist, shx);
    halves[tid] = (unsigned short)selbits;
    __syncthreads();
    if (tid < 128)
        wmask[(size_t)(b * NWIN + w) * 128 + tid] =
            (unsigned)halves[2 * tid] | ((unsigned)halves[2 * tid + 1] << 16);
}

// ---------------- votes: compact + 3-pass radix top-128 (<=256 cands), fp16 in/out ----------------
// fp16-derived keys have bits[12:0]==0, so after radix on ek bits [43:20]
// (= key[31:8]) surviving candidates have EXACTLY equal keys; tie-break is
// slot order (cand[] is d-ascending), identical to full u64 ranking.
__global__ __launch_bounds__(256) void k_votes(unsigned short* __restrict__ post,
                                               const unsigned* __restrict__ wmask,
                                               float* __restrict__ pooled) {
    __shared__ unsigned long long cand[256];
    __shared__ unsigned char selbyte[DD];
    __shared__ unsigned shx[16];
    __shared__ unsigned hcnt[256];
    const int tid = threadIdx.x, wid = tid >> 6, lane = tid & 63;
    const int t = blockIdx.x, b = blockIdx.y;
    unsigned short* rp = post + (size_t)(b * TT + t) * DD;
    int w1 = t >> 2, w0 = w1 - 1;
    unsigned mw0 = 0u, mw1 = 0u;
    if (w0 >= 0)        mw0 = wmask[(size_t)(b * NWIN + w0) * 128 + (tid >> 1)];
    if (w1 <= NWIN - 1) mw1 = wmask[(size_t)(b * NWIN + w1) * 128 + (tid >> 1)];
    const int bbase = (tid & 1) * 16;
    const unsigned ZKEY = 0x80000000u;
    ushort8 raw0 = *(const ushort8*)(rp + tid * 16);
    ushort8 raw1 = *(const ushort8*)(rp + tid * 16 + 8);
    float vals[16];
#pragma unroll
    for (int i = 0; i < 8; ++i) { vals[i] = h2f(raw0[i]); vals[8 + i] = h2f(raw1[i]); }
    unsigned keys[16];
#pragma unroll
    for (int i = 0; i < 16; ++i) {
        float cov = (float)(((mw0 >> (bbase + i)) & 1u) + ((mw1 >> (bbase + i)) & 1u));
        keys[i] = tokey(vals[i] * cov);
    }
    unsigned cpos = 0, cz = 0;
#pragma unroll
    for (int i = 0; i < 16; ++i) {
        cpos += (keys[i] > ZKEY);
        cz   += (keys[i] == ZKEY);
    }
    unsigned ppos = wave_prefix_incl(cpos);
    unsigned pz   = wave_prefix_incl(cz);
    if (lane == 63) { shx[wid] = ppos; shx[4 + wid] = pz; }
    __syncthreads();
    unsigned nz = shx[0] + shx[1] + shx[2] + shx[3];
    unsigned selbits = 0u;
    if (nz <= KTOP) {
        // all positives + first (KTOP-nz) zeros by index
        unsigned need = KTOP - nz;
        unsigned zr = pz - cz;
        if (wid > 0) zr += shx[4];
        if (wid > 1) zr += shx[5];
        if (wid > 2) zr += shx[6];
#pragma unroll
        for (int i = 0; i < 16; ++i) {
            bool sel = (keys[i] > ZKEY) || (keys[i] == ZKEY && zr < need);
            if (keys[i] == ZKEY) ++zr;
            selbits |= (sel ? 1u : 0u) << i;
        }
    } else {
        // compact candidates (d-ascending slot order)
        *(uint4*)(selbyte + tid * 16) = make_uint4(0u, 0u, 0u, 0u);
        unsigned off = ppos - cpos;          // exclusive within wave
        if (wid > 0) off += shx[0];
        if (wid > 1) off += shx[1];
        if (wid > 2) off += shx[2];
#pragma unroll
        for (int i = 0; i < 16; ++i) {
            if (keys[i] > ZKEY && off < 256u) {
                int d = tid * 16 + i;
                cand[off++] = ((unsigned long long)keys[i] << 12) | (unsigned)(4095 - d);
            }
        }
        __syncthreads();
        const unsigned m = nz < 256u ? nz : 256u;
        unsigned long long ek = (tid < (int)m) ? cand[tid] : 0ULL;
        unsigned Kr = KTOP;
        bool alive = (tid < (int)m);
        bool sel = false;
#pragma unroll
        for (int pass = 0; pass < 3; ++pass) {
            const int shift = 36 - pass * 8;
            hcnt[tid] = 0u;
            __syncthreads();
            unsigned dg = (unsigned)(ek >> shift) & 255u;
            if (alive) atomicAdd(&hcnt[dg], 1u);
            __syncthreads();
            unsigned v = hcnt[tid];
            unsigned s = wave_suffix_incl(v);
            if (lane == 0) shx[8 + wid] = s;
            __syncthreads();
            unsigned stot = s;
            if (wid == 0) stot += shx[9] + shx[10] + shx[11];
            else if (wid == 1) stot += shx[10] + shx[11];
            else if (wid == 2) stot += shx[11];
            unsigned above = stot - v;
            if (stot >= Kr && above < Kr) { shx[12] = (unsigned)tid; shx[13] = Kr - above; }
            __syncthreads();
            unsigned Td = shx[12];
            Kr = shx[13];
            if (alive) {
                if (dg > Td) { sel = true; alive = false; }
                else if (dg < Td) alive = false;
            }
        }
        // tie-break among exactly-equal keys: first Kr in slot (ascending d) order
        unsigned av = alive ? 1u : 0u;
        unsigned pa = wave_prefix_incl(av);
        if (lane == 63) shx[8 + wid] = pa;
        __syncthreads();
        unsigned er = pa - av;
        if (wid > 0) er += shx[8];
        if (wid > 1) er += shx[9];
        if (wid > 2) er += shx[10];
        if (alive && er < Kr) sel = true;
        if (sel) selbyte[4095 - (unsigned)(ek & 0xFFFu)] = 1;
        __syncthreads();
#pragma unroll
        for (int i = 0; i < 16; ++i)
            selbits |= (selbyte[tid * 16 + i] ? 1u : 0u) << i;
    }
    ushort8 o0, o1;
#pragma unroll
    for (int i = 0; i < 8; ++i) {
        bool s0 = (selbits >> i) & 1u;
        bool s1 = (selbits >> (8 + i)) & 1u;
        o0[i] = s0 ? raw0[i] : (unsigned short)0;
        o1[i] = s1 ? raw1[i] : (unsigned short)0;
        if (s0 && vals[i] != 0.f)     atomicAdd(&pooled[(size_t)b * DD + tid * 16 + i], vals[i]);
        if (s1 && vals[8 + i] != 0.f) atomicAdd(&pooled[(size_t)b * DD + tid * 16 + 8 + i], vals[8 + i]);
    }
    *(ushort8*)(rp + tid * 16)     = o0;
    *(ushort8*)(rp + tid * 16 + 8) = o1;
}

// ---------------- head ----------------
__device__ __forceinline__ float block_sum(float v, float* red) {
    const int tid = threadIdx.x;
    red[tid] = v;
    __syncthreads();
    for (int s = 128; s > 0; s >>= 1) { if (tid < s) red[tid] += red[tid + s]; __syncthreads(); }
    float r = red[0];
    __syncthreads();
    return r;
}

__global__ __launch_bounds__(256) void k_head_ln(const float* __restrict__ pooled,
                                                 const float* __restrict__ lng,
                                                 const float* __restrict__ lnb,
                                                 float* __restrict__ lnout) {
    __shared__ float red[256];
    const int b = blockIdx.x, tid = threadIdx.x;
    float pv[16];
    float s = 0.f;
#pragma unroll
    for (int q = 0; q < 4; ++q) {
        float4 u = *(const float4*)(pooled + (size_t)b * DD + tid * 16 + q * 4);
        pv[q * 4 + 0] = u.x * (1.f / TT); pv[q * 4 + 1] = u.y * (1.f / TT);
        pv[q * 4 + 2] = u.z * (1.f / TT); pv[q * 4 + 3] = u.w * (1.f / TT);
        s += pv[q * 4 + 0] + pv[q * 4 + 1] + pv[q * 4 + 2] + pv[q * 4 + 3];
    }
    float mean = block_sum(s, red) * (1.f / (float)DD);
    float vs = 0.f;
#pragma unroll
    for (int i = 0; i < 16; ++i) { float c = pv[i] - mean; vs += c * c; }
    float var = block_sum(vs, red) * (1.f / (float)DD);
    float inv = rsqrtf(var + 1e-5f);
#pragma unroll
    for (int q = 0; q < 4; ++q) {
        float4 g = *(const float4*)(lng + tid * 16 + q * 4);
        float4 bb = *(const float4*)(lnb + tid * 16 + q * 4);
        float4 o;
        o.x = (pv[q * 4 + 0] - mean) * inv * g.x + bb.x;
        o.y = (pv[q * 4 + 1] - mean) * inv * g.y + bb.y;
        o.z = (pv[q * 4 + 2] - mean) * inv * g.z + bb.z;
        o.w = (pv[q * 4 + 3] - mean) * inv * g.w + bb.w;
        *(float4*)(lnout + (size_t)b * DD + tid * 16 + q * 4) = o;
    }
}

__global__ __launch_bounds__(256) void k_head_mlp(const float* __restrict__ lnout,
                                                  const float* __restrict__ W1,
                                                  const float* __restrict__ b1,
                                                  float* __restrict__ h) {
    const int gw = (blockIdx.x * 256 + threadIdx.x) >> 6;   // 0..4095
    const int lane = threadIdx.x & 63;
    const int b = gw >> 8, row = gw & 255;
    const float* lp = lnout + (size_t)b * DD;
    const float* wr = W1 + (size_t)row * DD;
    float a = 0.f;
#pragma unroll
    for (int k = 0; k < DD / 64; ++k)
        a += lp[lane + 64 * k] * wr[lane + 64 * k];
#pragma unroll
    for (int off = 32; off > 0; off >>= 1) a += __shfl_down(a, off, 64);
    if (lane == 0) h[b * 256 + row] = fmaxf(a + b1[row], 0.f);
}

__global__ __launch_bounds__(256) void k_head_out(const float* __restrict__ h,
                                                  const float* __restrict__ W2,
                                                  const float* __restrict__ b2,
                                                  const float* __restrict__ sae,
                                                  float* __restrict__ out) {
    __shared__ float red[256];
    const int b = blockIdx.x, tid = threadIdx.x;
    float hv = h[b * 256 + tid];
    float l0 = block_sum(hv * W2[tid], red) + b2[0];
    float l1 = block_sum(hv * W2[256 + tid], red) + b2[1];
    if (tid == 0) {
        float m = fmaxf(l0, l1);
        float lse = m + logf(expf(l0 - m) + expf(l1 - m));
        out[2 * b] = l0 - lse;
        out[2 * b + 1] = l1 - lse;
        if (b == 0) out[32] = sae[0] * (1.f / (float)((size_t)NN * CC));
    }
}

// ---------------- launch ----------------
extern "C" void kernel_launch(void* const* d_in, const int* in_sizes, int n_in,
                              void* d_out, int out_size, void* d_ws, size_t ws_size,
                              hipStream_t stream) {
    const float* x    = (const float*)d_in[0];
    const float* Wenc = (const float*)d_in[1];
    const float* benc = (const float*)d_in[2];
    const float* Wdec = (const float*)d_in[3];
    const float* bdec = (const float*)d_in[4];
    const float* lng  = (const float*)d_in[5];
    const float* lnb  = (const float*)d_in[6];
    const float* W1   = (const float*)d_in[7];
    const float* b1   = (const float*)d_in[8];
    const float* W2   = (const float*)d_in[9];
    const float* b2   = (const float*)d_in[10];
    float* out = (float*)d_out;

    char* ws = (char*)d_ws;
    unsigned short* post  = (unsigned short*)(ws + 0);           //  67,108,864 (fp16 post / masked in place)
    unsigned short* xh16  = (unsigned short*)(ws + 67108864);    //  16,777,216 (fp16 x - b_dec; dead after gemm1)
    unsigned short* scr   = (unsigned short*)(ws + 83886080);    //  16,777,216 (scratch: hbuf)
    unsigned short* wh16  = (unsigned short*)(ws + 100663296);   //   8,388,608 (fp16 W_enc)
    unsigned short* wd16  = (unsigned short*)(ws + 109051904);   //   8,388,608 (fp16 W_dec)
    unsigned*       wmask = (unsigned*)(ws + 117440512);         //   1,040,384
    float*          pooled= (float*)(ws + 118480896);            //     262,144
    float*          sae   = (float*)(ws + 118743040);            //         256
    float*          gsum  = (float*)(ws + 118743296);            //  33,554,432  (optional)
    const bool use_gsum = ws_size >= (size_t)118743296 + 33554432;
    float* gptr = use_gsum ? gsum : nullptr;
    float* lnout = (float*)xh16;  // 256 KB, reuses dead xh16
    float* hbuf  = (float*)scr;   // 16 KB

    k_convert_all<<<dim3(16385), 256, 0, stream>>>(x, Wenc, Wdec, bdec, xh16, wh16, wd16, pooled);

    k_gemm_enc_256<<<dim3(DD / 256, NN / 256), 512, 0, stream>>>(xh16, wh16, benc, post, gptr);
    if (use_gsum)
        k_winsum_g<<<dim3(NWIN, BB), 256, 0, stream>>>(gsum, wmask);
    else
        k_winsum_p<<<dim3(NWIN, BB), 256, 0, stream>>>(post, wmask);
    k_votes<<<dim3(TT, BB), 256, 0, stream>>>(post, wmask, pooled);
    k_gemm_recon_256<<<dim3(CC / 128, NN / 256), 512, 0, stream>>>(post, wd16, bdec, x, sae);
    k_head_ln<<<dim3(BB), 256, 0, stream>>>(pooled, lng, lnb, lnout);
    k_head_mlp<<<dim3(1024), 256, 0, stream>>>(lnout, W1, b1, hbuf);
    k_head_out<<<dim3(BB), 256, 0, stream>>>(hbuf, W2, b2, sae, out);
}

// Round 4
// 423.618 us; speedup vs baseline: 1.0859x; 1.0859x over previous
//
#include <hip/hip_runtime.h>

// ---------------- constants ----------------
#define BB   16
#define TT   512
#define CC   1024
#define DD   4096
#define NN   (BB*TT)        // 8192
#define NWIN 127
#define KTOP 128

typedef __attribute__((ext_vector_type(8))) unsigned short ushort8;
typedef _Float16 half8 __attribute__((ext_vector_type(8)));
typedef __attribute__((ext_vector_type(4))) float f32x4;

// ---------------- helpers ----------------
__device__ __forceinline__ unsigned short f2h(float f) {
    union { _Float16 h; unsigned short u; } c;
    c.h = (_Float16)f;   // RNE
    return c.u;
}
__device__ __forceinline__ float h2f(unsigned short u) {
    union { unsigned short u; _Float16 h; } c;
    c.u = u;
    return (float)c.h;
}
__device__ __forceinline__ unsigned tokey(float f) {
    unsigned u = __float_as_uint(f);
    return (u & 0x80000000u) ? ~u : (u | 0x80000000u);
}
__device__ __forceinline__ void async_lds16(const void* g, void* l) {
    __builtin_amdgcn_global_load_lds((const __attribute__((address_space(1))) void*)g,
                                     (__attribute__((address_space(3))) void*)l, 16, 0, 0);
}

// phase fencing for the 8-phase schedule (r2-proven two-barrier form)
#define PH_SYNC() do { __builtin_amdgcn_sched_barrier(0); __builtin_amdgcn_s_barrier(); \
                       asm volatile("s_waitcnt lgkmcnt(0)" ::: "memory"); \
                       __builtin_amdgcn_sched_barrier(0); __builtin_amdgcn_s_setprio(1); } while (0)
#define PH_END()  do { __builtin_amdgcn_s_setprio(0); __builtin_amdgcn_sched_barrier(0); \
                       __builtin_amdgcn_s_barrier(); } while (0)

// wave-level scans (64 lanes)
__device__ __forceinline__ unsigned wave_prefix_incl(unsigned v) {
    int lane = threadIdx.x & 63;
#pragma unroll
    for (int off = 1; off < 64; off <<= 1) {
        unsigned n = __shfl_up(v, off, 64);
        if (lane >= off) v += n;
    }
    return v;
}
__device__ __forceinline__ unsigned wave_suffix_incl(unsigned v) {
    int lane = threadIdx.x & 63;
#pragma unroll
    for (int off = 1; off < 64; off <<= 1) {
        unsigned n = __shfl_down(v, off, 64);
        if (lane + off < 64) v += n;
    }
    return v;
}

// ---------------- top-128 radix select (dense, used by winsum) ----------------
__device__ __forceinline__ unsigned select_top128(const unsigned* keys,
                                                  unsigned* hist, unsigned* shx) {
    const int tid = threadIdx.x, wid = tid >> 6, lane = tid & 63;
    const unsigned ZKEY = 0x80000000u;
    unsigned cpos = 0, cz = 0;
#pragma unroll
    for (int i = 0; i < 16; ++i) {
        cpos += (keys[i] > ZKEY);
        cz   += (keys[i] == ZKEY);
    }
    unsigned ppos = wave_prefix_incl(cpos);
    unsigned pz   = wave_prefix_incl(cz);
    if (lane == 63) { shx[wid] = ppos; shx[4 + wid] = pz; }
    __syncthreads();
    unsigned nz = shx[0] + shx[1] + shx[2] + shx[3];
    unsigned selbits = 0u;
    if (nz <= KTOP) {
        unsigned need = KTOP - nz;
        unsigned zr = pz - cz;
        if (wid > 0) zr += shx[4];
        if (wid > 1) zr += shx[5];
        if (wid > 2) zr += shx[6];
#pragma unroll
        for (int i = 0; i < 16; ++i) {
            bool sel = (keys[i] > ZKEY) || (keys[i] == ZKEY && zr < need);
            if (keys[i] == ZKEY) ++zr;
            selbits |= (sel ? 1u : 0u) << i;
        }
        return selbits;
    }
    unsigned k2[16];
#pragma unroll
    for (int i = 0; i < 16; ++i) k2[i] = (keys[i] > ZKEY) ? keys[i] : 0u;
    unsigned prefix = 0u, pmask = 0u, Kr = KTOP;
    for (int shift = 24; shift >= 0; shift -= 8) {
        hist[tid] = 0u; hist[256 + tid] = 0u; hist[512 + tid] = 0u; hist[768 + tid] = 0u;
        __syncthreads();
        unsigned* h = hist + (wid << 8);
#pragma unroll
        for (int i = 0; i < 16; ++i)
            if (k2[i] && (k2[i] & pmask) == prefix) atomicAdd(&h[(k2[i] >> shift) & 255u], 1u);
        __syncthreads();
        unsigned v = hist[tid] + hist[256 + tid] + hist[512 + tid] + hist[768 + tid];
        unsigned s = wave_suffix_incl(v);
        if (lane == 0) shx[wid] = s;
        __syncthreads();
        unsigned stot = s;
        if (wid == 0) stot += shx[1] + shx[2] + shx[3];
        else if (wid == 1) stot += shx[2] + shx[3];
        else if (wid == 2) stot += shx[3];
        unsigned above = stot - v;
        if (stot >= Kr && above < Kr) { shx[8] = (unsigned)tid; shx[9] = Kr - above; }
        __syncthreads();
        prefix |= shx[8] << shift;
        pmask |= 0xFFu << shift;
        Kr = shx[9];
    }
    unsigned T = prefix, need = Kr;
    unsigned ce = 0;
#pragma unroll
    for (int i = 0; i < 16; ++i) ce += (k2[i] == T);
    unsigned pe = wave_prefix_incl(ce);
    __syncthreads();
    if (lane == 63) shx[4 + wid] = pe;
    __syncthreads();
    unsigned er = pe - ce;
    if (wid > 0) er += shx[4];
    if (wid > 1) er += shx[5];
    if (wid > 2) er += shx[6];
#pragma unroll
    for (int i = 0; i < 16; ++i) {
        bool sel = (k2[i] > T) || (k2[i] == T && er < need);
        if (k2[i] == T) ++er;
        selbits |= (sel ? 1u : 0u) << i;
    }
    return selbits;
}

// ---------------- merged converts + pooled/sae zeroing ----------------
__global__ __launch_bounds__(256) void k_convert_all(const float* __restrict__ x,
                                                     const float* __restrict__ Wenc,
                                                     const float* __restrict__ Wdec,
                                                     const float* __restrict__ bdec,
                                                     unsigned short* __restrict__ xh,
                                                     unsigned short* __restrict__ wh,
                                                     unsigned short* __restrict__ wdh,
                                                     float* __restrict__ pooled_zero) {
    const int bid = blockIdx.x;
    if (bid < 8192) {
        size_t i = (size_t)bid * 256 + threadIdx.x;       // x: 2M float4s
        float4 v = ((const float4*)x)[i];
        size_t c = (i * 4) & (CC - 1);
        v.x -= bdec[c]; v.y -= bdec[c + 1]; v.z -= bdec[c + 2]; v.w -= bdec[c + 3];
        uint2 o;
        o.x = (unsigned)f2h(v.x) | ((unsigned)f2h(v.y) << 16);
        o.y = (unsigned)f2h(v.z) | ((unsigned)f2h(v.w) << 16);
        ((uint2*)xh)[i] = o;
    } else if (bid < 12288) {
        size_t i = (size_t)(bid - 8192) * 256 + threadIdx.x;  // Wenc: 1M float4s
        float4 v = ((const float4*)Wenc)[i];
        uint2 o;
        o.x = (unsigned)f2h(v.x) | ((unsigned)f2h(v.y) << 16);
        o.y = (unsigned)f2h(v.z) | ((unsigned)f2h(v.w) << 16);
        ((uint2*)wh)[i] = o;
    } else if (bid < 16384) {
        size_t i = (size_t)(bid - 12288) * 256 + threadIdx.x; // Wdec: 1M float4s -> fp16
        float4 v = ((const float4*)Wdec)[i];
        uint2 o;
        o.x = (unsigned)f2h(v.x) | ((unsigned)f2h(v.y) << 16);
        o.y = (unsigned)f2h(v.z) | ((unsigned)f2h(v.w) << 16);
        ((uint2*)wdh)[i] = o;
    } else {
        const int n4 = (BB * DD + 64) / 4;
        for (int i = threadIdx.x; i < n4; i += 256)
            ((float4*)pooled_zero)[i] = make_float4(0.f, 0.f, 0.f, 0.f);
    }
}

// =====================================================================
// GEMM1: 256x256 tile, BK=64, 8 waves, 8-phase counted-vmcnt schedule.
// (r2-proven structure: in-phase ds_read, barrier+lgkmcnt(0), two
//  barriers per phase, vmcnt(6) gates at ph4/ph8.)
// post = relu(x @ WencT + b_enc) -> fp16, fused 4-row group sums.
// LDS: [buf][region A0,A1,B0,B1][128*64] fp16 = 128 KiB.
// =====================================================================
__global__ __launch_bounds__(512, 2) void k_gemm_enc_256(const unsigned short* __restrict__ Ah,
                                                         const unsigned short* __restrict__ Bh,
                                                         const float* __restrict__ bias,
                                                         unsigned short* __restrict__ Cout,
                                                         float* __restrict__ gsum) {
    __shared__ __align__(16) unsigned short lds[2][4][128 * 64];
    const int tid = threadIdx.x, w = tid >> 6, lane = tid & 63;
    const int bm = blockIdx.y * 256, bn = blockIdx.x * 256;
    const int wr = w >> 2, wc = w & 3;
    const int rA = lane & 15, q = lane >> 4;
    const int sc0 = (q ^ (rA & 7)) << 3, sc1 = ((4 + q) ^ (rA & 7)) << 3;
    const int s_rt = w * 16 + (lane >> 3);
    const int s_ct = ((lane & 7) ^ (lane >> 3)) * 8;
    const unsigned short* Abase = Ah + ((size_t)(bm + s_rt)) * 1024 + s_ct;
    const unsigned short* Bbase = Bh + ((size_t)(bn + s_rt)) * 1024 + s_ct;

    auto STAGE = [&](const unsigned short* gb, int rowoff, int kt, unsigned short* reg) {
        const unsigned short* g = gb + (size_t)rowoff * 1024 + (kt << 6);
        async_lds16(g, reg + w * 1024);
        async_lds16(g + 8 * 1024, reg + w * 1024 + 512);
    };

    half8 a[4][2], b[4][2];
    f32x4 acc[8][4] = {};

    auto RDA4 = [&](const unsigned short* reg) {
#pragma unroll
        for (int mf = 0; mf < 4; ++mf) {
            const unsigned short* p = reg + (wr * 64 + mf * 16 + rA) * 64;
            a[mf][0] = *(const half8*)(p + sc0);
            a[mf][1] = *(const half8*)(p + sc1);
        }
    };
    auto RDB2 = [&](const unsigned short* reg, int nb) {
#pragma unroll
        for (int nf = 0; nf < 2; ++nf) {
            const unsigned short* p = reg + (wc * 32 + nf * 16 + rA) * 64;
            b[nb + nf][0] = *(const half8*)(p + sc0);
            b[nb + nf][1] = *(const half8*)(p + sc1);
        }
    };
    auto MF = [&](int mb, int nb) {
#pragma unroll
        for (int kk = 0; kk < 2; ++kk)
#pragma unroll
            for (int mf = 0; mf < 4; ++mf)
#pragma unroll
                for (int nf = 0; nf < 2; ++nf)
                    acc[mb + mf][nb + nf] = __builtin_amdgcn_mfma_f32_16x16x32_f16(
                        a[mf][kk], b[nb + nf][kk], acc[mb + mf][nb + nf], 0, 0, 0);
    };

    // prologue: tile0 (A0,B0,A1,B1) -> buf0; tile1 (A0,B0,A1) -> buf1
    STAGE(Abase,   0, 0, lds[0][0]);
    STAGE(Bbase,   0, 0, lds[0][2]);
    STAGE(Abase, 128, 0, lds[0][1]);
    STAGE(Bbase, 128, 0, lds[0][3]);
    STAGE(Abase,   0, 1, lds[1][0]);
    STAGE(Bbase,   0, 1, lds[1][2]);
    STAGE(Abase, 128, 1, lds[1][1]);
    asm volatile("s_waitcnt vmcnt(6)" ::: "memory");
    __builtin_amdgcn_s_barrier();

    for (int i = 0; i < 8; ++i) {          // 2 K-tiles per iter, NT=16
        const int ko  = (2 * i + 1) & 15;
        const int ke  = (2 * i + 2) & 15;
        const int ko2 = (2 * i + 3) & 15;
        // ph1: tile e = A0 x B0
        RDA4(lds[0][0]); RDB2(lds[0][2], 0);
        STAGE(Bbase, 128, ko, lds[1][3]);
        PH_SYNC(); MF(0, 0); PH_END();
        // ph2: A0 x B1
        RDB2(lds[0][3], 2);
        STAGE(Abase, 0, ke, lds[0][0]);
        PH_SYNC(); MF(0, 2); PH_END();
        // ph3: A1 x B0
        RDA4(lds[0][1]);
        STAGE(Bbase, 0, ke, lds[0][2]);
        PH_SYNC(); MF(4, 0); PH_END();
        // ph4: A1 x B1 ; gate tile o
        STAGE(Abase, 128, ke, lds[0][1]);
        asm volatile("s_waitcnt vmcnt(6)" ::: "memory");
        PH_SYNC(); MF(4, 2); PH_END();
        // ph5: tile o = A0 x B0
        RDA4(lds[1][0]); RDB2(lds[1][2], 0);
        STAGE(Bbase, 128, ke, lds[0][3]);
        PH_SYNC(); MF(0, 0); PH_END();
        // ph6: A0 x B1
        RDB2(lds[1][3], 2);
        STAGE(Abase, 0, ko2, lds[1][0]);
        PH_SYNC(); MF(0, 2); PH_END();
        // ph7: A1 x B0
        RDA4(lds[1][1]);
        STAGE(Bbase, 0, ko2, lds[1][2]);
        PH_SYNC(); MF(4, 0); PH_END();
        // ph8: A1 x B1 ; gate tile e'
        STAGE(Abase, 128, ko2, lds[1][1]);
        asm volatile("s_waitcnt vmcnt(6)" ::: "memory");
        PH_SYNC(); MF(4, 2); PH_END();
    }

    // ---------------- epilogue: bias+relu -> fp16 Cout, fused gsum ----------------
    asm volatile("s_waitcnt vmcnt(0)" ::: "memory");
    __syncthreads();
    float* cbuf = (float*)&lds[0][0][0];   // [128][256] fp32, bank-XOR-swizzled
    const int cl = rA, qr = q * 4;
    float bv[4];
#pragma unroll
    for (int nf = 0; nf < 4; ++nf)
        bv[nf] = bias[bn + ((nf < 2) ? wc * 32 + nf * 16 : 128 + wc * 32 + (nf - 2) * 16) + cl];
    const int rg = tid >> 4, seg = tid & 15;
#pragma unroll
    for (int p = 0; p < 2; ++p) {
        if (p) __syncthreads();
#pragma unroll
        for (int mf = 0; mf < 4; ++mf) {
            int lrow0 = wr * 64 + mf * 16 + qr;
#pragma unroll
            for (int nf = 0; nf < 4; ++nf) {
                int col = ((nf < 2) ? wc * 32 + nf * 16 : 128 + wc * 32 + (nf - 2) * 16) + cl;
#pragma unroll
                for (int r = 0; r < 4; ++r) {
                    int lrow = lrow0 + r;
                    float v = acc[p * 4 + mf][nf][r] + bv[nf];
                    v = v > 0.f ? v : 0.f;
                    cbuf[lrow * 256 + (col ^ (((lrow >> 2) & 7) << 2))] = v;
                }
            }
        }
        __syncthreads();
        f32x4 gs0 = {}, gs1 = {}, gs2 = {}, gs3 = {};
#pragma unroll
        for (int i2 = 0; i2 < 4; ++i2) {
            const int lrow = rg * 4 + i2;
            const f32x4* crow = (const f32x4*)cbuf + lrow * 64;
            f32x4 v0 = crow[(seg * 4 + 0) ^ (rg & 7)];
            f32x4 v1 = crow[(seg * 4 + 1) ^ (rg & 7)];
            f32x4 v2 = crow[(seg * 4 + 2) ^ (rg & 7)];
            f32x4 v3 = crow[(seg * 4 + 3) ^ (rg & 7)];
            uint4 o0, o1;
            o0.x = (unsigned)f2h(v0[0]) | ((unsigned)f2h(v0[1]) << 16);
            o0.y = (unsigned)f2h(v0[2]) | ((unsigned)f2h(v0[3]) << 16);
            o0.z = (unsigned)f2h(v1[0]) | ((unsigned)f2h(v1[1]) << 16);
            o0.w = (unsigned)f2h(v1[2]) | ((unsigned)f2h(v1[3]) << 16);
            o1.x = (unsigned)f2h(v2[0]) | ((unsigned)f2h(v2[1]) << 16);
            o1.y = (unsigned)f2h(v2[2]) | ((unsigned)f2h(v2[3]) << 16);
            o1.z = (unsigned)f2h(v3[0]) | ((unsigned)f2h(v3[1]) << 16);
            o1.w = (unsigned)f2h(v3[2]) | ((unsigned)f2h(v3[3]) << 16);
            size_t gr = (size_t)(bm + p * 128 + lrow) * 4096 + bn + seg * 16;
            *(uint4*)&Cout[gr] = o0;
            *(uint4*)&Cout[gr + 8] = o1;
            gs0 += v0; gs1 += v1; gs2 += v2; gs3 += v3;
        }
        if (gsum) {
            size_t gr = ((size_t)(bm >> 2) + p * 32 + rg) * 4096 + bn + seg * 16;
            *(f32x4*)&gsum[gr + 0]  = gs0;
            *(f32x4*)&gsum[gr + 4]  = gs1;
            *(f32x4*)&gsum[gr + 8]  = gs2;
            *(f32x4*)&gsum[gr + 12] = gs3;
        }
    }
}

// =====================================================================
// GEMM2: 256x128 tile, BK=64, 8 waves (4Mx2N), 8-phase counted-vmcnt.
// (r2-proven structure.) recon + fused sae loss. LDS 96 KiB.
// =====================================================================
__global__ __launch_bounds__(512, 2) void k_gemm_recon_256(const unsigned short* __restrict__ Ap,
                                                           const unsigned short* __restrict__ Bp,
                                                           const float* __restrict__ bdec,
                                                           const float* __restrict__ X,
                                                           float* __restrict__ sae) {
    __shared__ __align__(16) unsigned short lds[2][3][128 * 64];
    __shared__ float red[512];
    const int tid = threadIdx.x, w = tid >> 6, lane = tid & 63;
    const int bm = blockIdx.y * 256, bn = blockIdx.x * 128;
    const int wr = w >> 1, wc = w & 1;
    const int rA = lane & 15, q = lane >> 4;
    const int sc0 = (q ^ (rA & 7)) << 3, sc1 = ((4 + q) ^ (rA & 7)) << 3;
    const int s_rt = w * 16 + (lane >> 3);
    const int s_ct = ((lane & 7) ^ (lane >> 3)) * 8;
    const unsigned short* Abase = Ap + ((size_t)(bm + s_rt)) * 4096 + s_ct;
    const unsigned short* Bbase = Bp + ((size_t)(bn + s_rt)) * 4096 + s_ct;

    auto STAGE = [&](const unsigned short* gb, int rowoff, int kt, unsigned short* reg) {
        const unsigned short* g = gb + (size_t)rowoff * 4096 + (kt << 6);
        async_lds16(g, reg + w * 1024);
        async_lds16(g + 8 * 4096, reg + w * 1024 + 512);
    };

    half8 a[2][2], b[4][2];
    f32x4 acc[4][4] = {};

    auto RDA2 = [&](const unsigned short* reg) {
#pragma unroll
        for (int mf = 0; mf < 2; ++mf) {
            const unsigned short* p = reg + (wr * 32 + mf * 16 + rA) * 64;
            a[mf][0] = *(const half8*)(p + sc0);
            a[mf][1] = *(const half8*)(p + sc1);
        }
    };
    auto RDB2 = [&](const unsigned short* reg, int nb) {
#pragma unroll
        for (int nf = 0; nf < 2; ++nf) {
            const unsigned short* p = reg + ((nb ? 64 : 0) + wc * 32 + nf * 16 + rA) * 64;
            b[nb + nf][0] = *(const half8*)(p + sc0);
            b[nb + nf][1] = *(const half8*)(p + sc1);
        }
    };
    auto MF = [&](int mb, int nb) {
#pragma unroll
        for (int kk = 0; kk < 2; ++kk)
#pragma unroll
            for (int mf = 0; mf < 2; ++mf)
#pragma unroll
                for (int nf = 0; nf < 2; ++nf)
                    acc[mb + mf][nb + nf] = __builtin_amdgcn_mfma_f32_16x16x32_f16(
                        a[mf][kk], b[nb + nf][kk], acc[mb + mf][nb + nf], 0, 0, 0);
    };

    // prologue: tile0 (A0,B,A1) -> buf0; tile1 (A0,B) -> buf1
    STAGE(Abase,   0, 0, lds[0][0]);
    STAGE(Bbase,   0, 0, lds[0][2]);
    STAGE(Abase, 128, 0, lds[0][1]);
    STAGE(Abase,   0, 1, lds[1][0]);
    STAGE(Bbase,   0, 1, lds[1][2]);
    asm volatile("s_waitcnt vmcnt(4)" ::: "memory");
    __builtin_amdgcn_s_barrier();

    for (int i = 0; i < 32; ++i) {         // 2 K-tiles per iter, NT=64
        const int ko  = (2 * i + 1) & 63;
        const int ke  = (2 * i + 2) & 63;
        const int ko2 = (2 * i + 3) & 63;
        // ph1: tile e = A0 x B(lo)
        RDA2(lds[0][0]); RDB2(lds[0][2], 0);
        STAGE(Abase, 128, ko, lds[1][1]);
        PH_SYNC(); MF(0, 0); PH_END();
        // ph2: A0 x B(hi)
        RDB2(lds[0][2], 2);
        STAGE(Abase, 0, ke, lds[0][0]);
        PH_SYNC(); MF(0, 2); PH_END();
        // ph3: A1 x B(lo)
        RDA2(lds[0][1]);
        STAGE(Bbase, 0, ke, lds[0][2]);
        PH_SYNC(); MF(2, 0); PH_END();
        // ph4: A1 x B(hi) ; gate tile o
        asm volatile("s_waitcnt vmcnt(4)" ::: "memory");
        PH_SYNC(); MF(2, 2); PH_END();
        // ph5: tile o = A0 x B(lo)
        RDA2(lds[1][0]); RDB2(lds[1][2], 0);
        STAGE(Abase, 128, ke, lds[0][1]);
        PH_SYNC(); MF(0, 0); PH_END();
        // ph6: A0 x B(hi)
        RDB2(lds[1][2], 2);
        STAGE(Abase, 0, ko2, lds[1][0]);
        PH_SYNC(); MF(0, 2); PH_END();
        // ph7: A1 x B(lo)
        RDA2(lds[1][1]);
        STAGE(Bbase, 0, ko2, lds[1][2]);
        PH_SYNC(); MF(2, 0); PH_END();
        // ph8: A1 x B(hi) ; gate tile e'
        asm volatile("s_waitcnt vmcnt(4)" ::: "memory");
        PH_SYNC(); MF(2, 2); PH_END();
    }

    // ---------------- epilogue: fused sae ----------------
    asm volatile("s_waitcnt vmcnt(0)" ::: "memory");
    const int cl = rA, qr = q * 4;
    float lsum = 0.f;
#pragma unroll
    for (int mf = 0; mf < 4; ++mf) {
        int row0 = bm + ((mf < 2) ? wr * 32 + mf * 16 : 128 + wr * 32 + (mf - 2) * 16) + qr;
#pragma unroll
        for (int nf = 0; nf < 4; ++nf) {
            int col = bn + ((nf < 2) ? wc * 32 + nf * 16 : 64 + wc * 32 + (nf - 2) * 16) + cl;
            float bvv = bdec[col];
#pragma unroll
            for (int r = 0; r < 4; ++r) {
                float v = acc[mf][nf][r] + bvv - X[(size_t)(row0 + r) * 1024 + col];
                lsum += v * v;
            }
        }
    }
    red[tid] = lsum;
    __syncthreads();
    for (int s = 256; s > 0; s >>= 1) { if (tid < s) red[tid] += red[tid + s]; __syncthreads(); }
    if (tid == 0) atomicAdd(sae, red[0]);
}

// ---------------- window top-128 from fused group sums ----------------
__global__ __launch_bounds__(256) void k_winsum_g(const float* __restrict__ gsum,
                                                  unsigned* __restrict__ wmask) {
    __shared__ unsigned hist[1024];
    __shared__ unsigned shx[16];
    __shared__ unsigned short halves[256];
    const int tid = threadIdx.x, w = blockIdx.x, b = blockIdx.y;
    const float* g0 = gsum + ((size_t)(b * 128 + w)) * DD + tid * 16;
    const float* g1 = g0 + DD;
    unsigned keys[16];
#pragma unroll
    for (int q = 0; q < 4; ++q) {
        float4 u = *(const float4*)(g0 + q * 4);
        float4 v = *(const float4*)(g1 + q * 4);
        keys[q * 4 + 0] = tokey(u.x + v.x);
        keys[q * 4 + 1] = tokey(u.y + v.y);
        keys[q * 4 + 2] = tokey(u.z + v.z);
        keys[q * 4 + 3] = tokey(u.w + v.w);
    }
    unsigned selbits = select_top128(keys, hist, shx);
    halves[tid] = (unsigned short)selbits;
    __syncthreads();
    if (tid < 128)
        wmask[(size_t)(b * NWIN + w) * 128 + tid] =
            (unsigned)halves[2 * tid] | ((unsigned)halves[2 * tid + 1] << 16);
}

// fallback: window sums read from fp16 post directly (if ws too small for gsum)
__global__ __launch_bounds__(256) void k_winsum_p(const unsigned short* __restrict__ post,
                                                  unsigned* __restrict__ wmask) {
    __shared__ unsigned hist[1024];
    __shared__ unsigned shx[16];
    __shared__ unsigned short halves[256];
    const int tid = threadIdx.x, w = blockIdx.x, b = blockIdx.y;
    const unsigned short* base = post + (size_t)(b * TT + w * 4) * DD + tid * 16;
    float s[16] = {};
#pragma unroll
    for (int j = 0; j < 8; ++j) {
        const unsigned short* rp = base + (size_t)j * DD;
        ushort8 u0 = *(const ushort8*)rp;
        ushort8 u1 = *(const ushort8*)(rp + 8);
#pragma unroll
        for (int i = 0; i < 8; ++i) { s[i] += h2f(u0[i]); s[8 + i] += h2f(u1[i]); }
    }
    unsigned keys[16];
#pragma unroll
    for (int i = 0; i < 16; ++i) keys[i] = tokey(s[i]);
    unsigned selbits = select_top128(keys, hist, shx);
    halves[tid] = (unsigned short)selbits;
    __syncthreads();
    if (tid < 128)
        wmask[(size_t)(b * NWIN + w) * 128 + tid] =
            (unsigned)halves[2 * tid] | ((unsigned)halves[2 * tid + 1] << 16);
}

// ---------------- votes: 4 rows per block (shared masks), radix top-128 ----------------
// Rows t in a group of 4 share w1 = t>>2, so masks load once. Pooled
// contributions accumulate in registers across the 4 rows -> 1 atomic/d.
__global__ __launch_bounds__(256) void k_votes(unsigned short* __restrict__ post,
                                               const unsigned* __restrict__ wmask,
                                               float* __restrict__ pooled) {
    __shared__ unsigned long long cand[256];
    __shared__ unsigned char selbyte[DD];
    __shared__ unsigned shx[16];
    __shared__ unsigned hcnt[256];
    const int tid = threadIdx.x, wid = tid >> 6, lane = tid & 63;
    const int g = blockIdx.x, b = blockIdx.y;
    int w1 = g, w0 = g - 1;
    unsigned mw0 = 0u, mw1 = 0u;
    if (w0 >= 0)        mw0 = wmask[(size_t)(b * NWIN + w0) * 128 + (tid >> 1)];
    if (w1 <= NWIN - 1) mw1 = wmask[(size_t)(b * NWIN + w1) * 128 + (tid >> 1)];
    const int bbase = (tid & 1) * 16;
    const unsigned ZKEY = 0x80000000u;
    float psum[16];
#pragma unroll
    for (int i = 0; i < 16; ++i) psum[i] = 0.f;

    for (int r = 0; r < 4; ++r) {
        unsigned short* rp = post + (size_t)(b * TT + g * 4 + r) * DD;
        ushort8 raw0 = *(const ushort8*)(rp + tid * 16);
        ushort8 raw1 = *(const ushort8*)(rp + tid * 16 + 8);
        float vals[16];
#pragma unroll
        for (int i = 0; i < 8; ++i) { vals[i] = h2f(raw0[i]); vals[8 + i] = h2f(raw1[i]); }
        unsigned keys[16];
#pragma unroll
        for (int i = 0; i < 16; ++i) {
            float cov = (float)(((mw0 >> (bbase + i)) & 1u) + ((mw1 >> (bbase + i)) & 1u));
            keys[i] = tokey(vals[i] * cov);
        }
        unsigned cpos = 0, cz = 0;
#pragma unroll
        for (int i = 0; i < 16; ++i) {
            cpos += (keys[i] > ZKEY);
            cz   += (keys[i] == ZKEY);
        }
        unsigned ppos = wave_prefix_incl(cpos);
        unsigned pz   = wave_prefix_incl(cz);
        __syncthreads();   // protect shx (and selbyte from previous row) before reuse
        if (lane == 63) { shx[wid] = ppos; shx[4 + wid] = pz; }
        __syncthreads();
        unsigned nz = shx[0] + shx[1] + shx[2] + shx[3];
        unsigned selbits = 0u;
        if (nz <= KTOP) {
            unsigned need = KTOP - nz;
            unsigned zr = pz - cz;
            if (wid > 0) zr += shx[4];
            if (wid > 1) zr += shx[5];
            if (wid > 2) zr += shx[6];
#pragma unroll
            for (int i = 0; i < 16; ++i) {
                bool sel = (keys[i] > ZKEY) || (keys[i] == ZKEY && zr < need);
                if (keys[i] == ZKEY) ++zr;
                selbits |= (sel ? 1u : 0u) << i;
            }
        } else {
            // compact candidates (d-ascending slot order)
            *(uint4*)(selbyte + tid * 16) = make_uint4(0u, 0u, 0u, 0u);
            unsigned off = ppos - cpos;          // exclusive within wave
            if (wid > 0) off += shx[0];
            if (wid > 1) off += shx[1];
            if (wid > 2) off += shx[2];
#pragma unroll
            for (int i = 0; i < 16; ++i) {
                if (keys[i] > ZKEY && off < 256u) {
                    int d = tid * 16 + i;
                    cand[off++] = ((unsigned long long)keys[i] << 12) | (unsigned)(4095 - d);
                }
            }
            __syncthreads();
            const unsigned m = nz < 256u ? nz : 256u;
            unsigned long long ek = (tid < (int)m) ? cand[tid] : 0ULL;
            unsigned Kr = KTOP;
            bool alive = (tid < (int)m);
            bool sel = false;
#pragma unroll
            for (int pass = 0; pass < 3; ++pass) {
                const int shift = 36 - pass * 8;
                hcnt[tid] = 0u;
                __syncthreads();
                unsigned dg = (unsigned)(ek >> shift) & 255u;
                if (alive) atomicAdd(&hcnt[dg], 1u);
                __syncthreads();
                unsigned v = hcnt[tid];
                unsigned s = wave_suffix_incl(v);
                if (lane == 0) shx[8 + wid] = s;
                __syncthreads();
                unsigned stot = s;
                if (wid == 0) stot += shx[9] + shx[10] + shx[11];
                else if (wid == 1) stot += shx[10] + shx[11];
                else if (wid == 2) stot += shx[11];
                unsigned above = stot - v;
                if (stot >= Kr && above < Kr) { shx[12] = (unsigned)tid; shx[13] = Kr - above; }
                __syncthreads();
                unsigned Td = shx[12];
                Kr = shx[13];
                if (alive) {
                    if (dg > Td) { sel = true; alive = false; }
                    else if (dg < Td) alive = false;
                }
            }
            // tie-break among exactly-equal keys: first Kr in slot order
            unsigned av = alive ? 1u : 0u;
            unsigned pa = wave_prefix_incl(av);
            if (lane == 63) shx[8 + wid] = pa;
            __syncthreads();
            unsigned er = pa - av;
            if (wid > 0) er += shx[8];
            if (wid > 1) er += shx[9];
            if (wid > 2) er += shx[10];
            if (alive && er < Kr) sel = true;
            if (sel) selbyte[4095 - (unsigned)(ek & 0xFFFu)] = 1;
            __syncthreads();
#pragma unroll
            for (int i = 0; i < 16; ++i)
                selbits |= (selbyte[tid * 16 + i] ? 1u : 0u) << i;
        }
        ushort8 o0, o1;
#pragma unroll
        for (int i = 0; i < 8; ++i) {
            bool s0 = (selbits >> i) & 1u;
            bool s1 = (selbits >> (8 + i)) & 1u;
            o0[i] = s0 ? raw0[i] : (unsigned short)0;
            o1[i] = s1 ? raw1[i] : (unsigned short)0;
            if (s0) psum[i]     += vals[i];
            if (s1) psum[8 + i] += vals[8 + i];
        }
        *(ushort8*)(rp + tid * 16)     = o0;
        *(ushort8*)(rp + tid * 16 + 8) = o1;
    }
#pragma unroll
    for (int i = 0; i < 16; ++i)
        if (psum[i] != 0.f) atomicAdd(&pooled[(size_t)b * DD + tid * 16 + i], psum[i]);
}

// ---------------- head ----------------
__device__ __forceinline__ float block_sum(float v, float* red) {
    const int tid = threadIdx.x;
    red[tid] = v;
    __syncthreads();
    for (int s = 128; s > 0; s >>= 1) { if (tid < s) red[tid] += red[tid + s]; __syncthreads(); }
    float r = red[0];
    __syncthreads();
    return r;
}

__global__ __launch_bounds__(256) void k_head_ln(const float* __restrict__ pooled,
                                                 const float* __restrict__ lng,
                                                 const float* __restrict__ lnb,
                                                 float* __restrict__ lnout) {
    __shared__ float red[256];
    const int b = blockIdx.x, tid = threadIdx.x;
    float pv[16];
    float s = 0.f;
#pragma unroll
    for (int q = 0; q < 4; ++q) {
        float4 u = *(const float4*)(pooled + (size_t)b * DD + tid * 16 + q * 4);
        pv[q * 4 + 0] = u.x * (1.f / TT); pv[q * 4 + 1] = u.y * (1.f / TT);
        pv[q * 4 + 2] = u.z * (1.f / TT); pv[q * 4 + 3] = u.w * (1.f / TT);
        s += pv[q * 4 + 0] + pv[q * 4 + 1] + pv[q * 4 + 2] + pv[q * 4 + 3];
    }
    float mean = block_sum(s, red) * (1.f / (float)DD);
    float vs = 0.f;
#pragma unroll
    for (int i = 0; i < 16; ++i) { float c = pv[i] - mean; vs += c * c; }
    float var = block_sum(vs, red) * (1.f / (float)DD);
    float inv = rsqrtf(var + 1e-5f);
#pragma unroll
    for (int q = 0; q < 4; ++q) {
        float4 g = *(const float4*)(lng + tid * 16 + q * 4);
        float4 bb = *(const float4*)(lnb + tid * 16 + q * 4);
        float4 o;
        o.x = (pv[q * 4 + 0] - mean) * inv * g.x + bb.x;
        o.y = (pv[q * 4 + 1] - mean) * inv * g.y + bb.y;
        o.z = (pv[q * 4 + 2] - mean) * inv * g.z + bb.z;
        o.w = (pv[q * 4 + 3] - mean) * inv * g.w + bb.w;
        *(float4*)(lnout + (size_t)b * DD + tid * 16 + q * 4) = o;
    }
}

__global__ __launch_bounds__(256) void k_head_mlp(const float* __restrict__ lnout,
                                                  const float* __restrict__ W1,
                                                  const float* __restrict__ b1,
                                                  float* __restrict__ h) {
    const int gw = (blockIdx.x * 256 + threadIdx.x) >> 6;   // 0..4095
    const int lane = threadIdx.x & 63;
    const int b = gw >> 8, row = gw & 255;
    const float* lp = lnout + (size_t)b * DD;
    const float* wr = W1 + (size_t)row * DD;
    float a = 0.f;
#pragma unroll
    for (int k = 0; k < DD / 64; ++k)
        a += lp[lane + 64 * k] * wr[lane + 64 * k];
#pragma unroll
    for (int off = 32; off > 0; off >>= 1) a += __shfl_down(a, off, 64);
    if (lane == 0) h[b * 256 + row] = fmaxf(a + b1[row], 0.f);
}

__global__ __launch_bounds__(256) void k_head_out(const float* __restrict__ h,
                                                  const float* __restrict__ W2,
                                                  const float* __restrict__ b2,
                                                  const float* __restrict__ sae,
                                                  float* __restrict__ out) {
    __shared__ float red[256];
    const int b = blockIdx.x, tid = threadIdx.x;
    float hv = h[b * 256 + tid];
    float l0 = block_sum(hv * W2[tid], red) + b2[0];
    float l1 = block_sum(hv * W2[256 + tid], red) + b2[1];
    if (tid == 0) {
        float m = fmaxf(l0, l1);
        float lse = m + logf(expf(l0 - m) + expf(l1 - m));
        out[2 * b] = l0 - lse;
        out[2 * b + 1] = l1 - lse;
        if (b == 0) out[32] = sae[0] * (1.f / (float)((size_t)NN * CC));
    }
}

// ---------------- launch ----------------
extern "C" void kernel_launch(void* const* d_in, const int* in_sizes, int n_in,
                              void* d_out, int out_size, void* d_ws, size_t ws_size,
                              hipStream_t stream) {
    const float* x    = (const float*)d_in[0];
    const float* Wenc = (const float*)d_in[1];
    const float* benc = (const float*)d_in[2];
    const float* Wdec = (const float*)d_in[3];
    const float* bdec = (const float*)d_in[4];
    const float* lng  = (const float*)d_in[5];
    const float* lnb  = (const float*)d_in[6];
    const float* W1   = (const float*)d_in[7];
    const float* b1   = (const float*)d_in[8];
    const float* W2   = (const float*)d_in[9];
    const float* b2   = (const float*)d_in[10];
    float* out = (float*)d_out;

    char* ws = (char*)d_ws;
    unsigned short* post  = (unsigned short*)(ws + 0);           //  67,108,864 (fp16 post / masked in place)
    unsigned short* xh16  = (unsigned short*)(ws + 67108864);    //  16,777,216 (fp16 x - b_dec; dead after gemm1)
    unsigned short* scr   = (unsigned short*)(ws + 83886080);    //  16,777,216 (scratch: hbuf)
    unsigned short* wh16  = (unsigned short*)(ws + 100663296);   //   8,388,608 (fp16 W_enc)
    unsigned short* wd16  = (unsigned short*)(ws + 109051904);   //   8,388,608 (fp16 W_dec)
    unsigned*       wmask = (unsigned*)(ws + 117440512);         //   1,040,384
    float*          pooled= (float*)(ws + 118480896);            //     262,144
    float*          sae   = (float*)(ws + 118743040);            //         256
    float*          gsum  = (float*)(ws + 118743296);            //  33,554,432  (optional)
    const bool use_gsum = ws_size >= (size_t)118743296 + 33554432;
    float* gptr = use_gsum ? gsum : nullptr;
    float* lnout = (float*)xh16;  // 256 KB, reuses dead xh16
    float* hbuf  = (float*)scr;   // 16 KB

    k_convert_all<<<dim3(16385), 256, 0, stream>>>(x, Wenc, Wdec, bdec, xh16, wh16, wd16, pooled);

    k_gemm_enc_256<<<dim3(DD / 256, NN / 256), 512, 0, stream>>>(xh16, wh16, benc, post, gptr);
    if (use_gsum)
        k_winsum_g<<<dim3(NWIN, BB), 256, 0, stream>>>(gsum, wmask);
    else
        k_winsum_p<<<dim3(NWIN, BB), 256, 0, stream>>>(post, wmask);
    k_votes<<<dim3(TT / 4, BB), 256, 0, stream>>>(post, wmask, pooled);
    k_gemm_recon_256<<<dim3(CC / 128, NN / 256), 512, 0, stream>>>(post, wd16, bdec, x, sae);
    k_head_ln<<<dim3(BB), 256, 0, stream>>>(pooled, lng, lnb, lnout);
    k_head_mlp<<<dim3(1024), 256, 0, stream>>>(lnout, W1, b1, hbuf);
    k_head_out<<<dim3(BB), 256, 0, stream>>>(hbuf, W2, b2, sae, out);
}